// Round 6
// baseline (4505.257 us; speedup 1.0000x reference)
//
#include <hip/hip_runtime.h>
#include <hip/hip_bf16.h>
#include <stdint.h>

// Problem constants
#define NB 128    // batch
#define NT 512    // time steps
#define ND 256    // input dim
#define NH 1024   // hidden dim
#define NZ 128    // latent dim
#define NG 4096   // 4*NH gate width
#define NK 1280   // ND + NH combined K

typedef __attribute__((ext_vector_type(8))) __bf16 bf16x8;
typedef __attribute__((ext_vector_type(4))) __bf16 bf16x4;
typedef __attribute__((ext_vector_type(4))) float floatx4;

__device__ __forceinline__ float sigmoidf_(float x) { return 1.0f / (1.0f + expf(-x)); }
__device__ __forceinline__ float softplusf_(float x) {
  return (x > 0.0f) ? (x + log1pf(expf(-x))) : log1pf(expf(x));
}

// ---------------------------------------------------------------------------
// Kernel 1: convert x (B,T,D) fp32 -> xb (T,B,D) bf16
// ---------------------------------------------------------------------------
__global__ __launch_bounds__(256) void convert_x_kernel(
    const float4* __restrict__ x, __bf16* __restrict__ xb) {
  int i = blockIdx.x * 256 + threadIdx.x;   // [0, B*T*D/4)
  int d4 = i & 63;                          // float4 index within row of 256
  int bt = i >> 6;                          // b*512 + t
  int b = bt >> 9;
  int t = bt & 511;
  float4 v = x[i];
  bf16x4 o;
  o[0] = (__bf16)v.x; o[1] = (__bf16)v.y; o[2] = (__bf16)v.z; o[3] = (__bf16)v.w;
  *(bf16x4*)(xb + ((t * NB + b) * ND + d4 * 4)) = o;
}

// ---------------------------------------------------------------------------
// Kernel 2: persistent LSTM.
// R5 structure, ONE change: __launch_bounds__(512, 1).
// Evidence: VGPR_Count pinned at 116/124/120 across R2/R4/R5 -> the second
// launch_bounds arg behaves as CUDA min-BLOCKS-per-CU: (512,2) => 16 waves/CU
// => 4 waves/SIMD => 512-reg pool/4 = 128-VGPR cap, which spilled the 160-reg
// weight array every time. (512,1) => 8 waves/CU => 2/SIMD => 256-VGPR cap.
// Grid 256 WGs x 512 thr (1 WG/CU, cooperative). WG = (m_blk = blockIdx&7,
// n_blk = blockIdx>>3): batch rows [m_blk*16, +16), h-cols [n_blk*32, +32).
// Wave w: gate g = w>>1 (i,f,g,o), col-half = w&1 -> 16 gate cols, FULL
// K=1280: 40 named bf16x8 fragments (160 VGPRs).
// Cross-WG h exchange + slot barrier: agent-scope atomics only (no fences,
// no L2 invalidation). x tile prefetched into regs before the barrier poll.
// ---------------------------------------------------------------------------
__global__ __launch_bounds__(512, 1) void lstm_persistent(
    const __bf16* __restrict__ xb,    // (T, B, D) bf16
    const float* __restrict__ W,      // (D, 4H)
    const float* __restrict__ U,      // (H, 4H)
    const float* __restrict__ bias,   // (4H)
    __bf16* __restrict__ hbuf,        // 2 * B * H bf16 (double buffer)
    float* __restrict__ hlast,        // B * H fp32
    unsigned int* __restrict__ slots) // 256 barrier slots (8 groups x 32)
{
  const int tid = threadIdx.x;
  const int wg = blockIdx.x;
  const int m_blk = wg & 7;
  const int n_blk = wg >> 3;
  const int wave = tid >> 6;
  const int lane = tid & 63;
  const int q = lane >> 4;     // k-quad
  const int n16 = lane & 15;   // MFMA col within 16-col tile
  const int g = wave >> 1;     // gate index 0..3 (i,f,g,o)
  const int half = wave & 1;   // which 16 of the 32 h-cols

  __shared__ __bf16 As[16 * 1288];  // A tile, rows padded 1280 -> 1288
  __shared__ float Gs[16][132];     // gates, padded 128 -> 132
  __shared__ __bf16 Hso[16][32];    // h output tile

  // ---- Load persistent B fragments as 40 NAMED bf16x8 (160 VGPRs) ----
  const int gc = g * NH + n_blk * 32 + half * 16 + n16;  // global gate column
#define LB(ii)                                                            \
  bf16x8 B##ii;                                                           \
  {                                                                       \
    const int k0 = (ii) * 32;                                             \
    const float* s = (k0 < 256) ? (W + k0 * NG + gc)                      \
                                : (U + (k0 - 256) * NG + gc);             \
    bf16x8 v;                                                             \
    v[0] = (__bf16)s[(q * 8 + 0) * NG]; v[1] = (__bf16)s[(q * 8 + 1) * NG]; \
    v[2] = (__bf16)s[(q * 8 + 2) * NG]; v[3] = (__bf16)s[(q * 8 + 3) * NG]; \
    v[4] = (__bf16)s[(q * 8 + 4) * NG]; v[5] = (__bf16)s[(q * 8 + 5) * NG]; \
    v[6] = (__bf16)s[(q * 8 + 6) * NG]; v[7] = (__bf16)s[(q * 8 + 7) * NG]; \
    B##ii = v;                                                            \
  }
  LB(0) LB(1) LB(2) LB(3) LB(4) LB(5) LB(6) LB(7) LB(8) LB(9)
  LB(10) LB(11) LB(12) LB(13) LB(14) LB(15) LB(16) LB(17) LB(18) LB(19)
  LB(20) LB(21) LB(22) LB(23) LB(24) LB(25) LB(26) LB(27) LB(28) LB(29)
  LB(30) LB(31) LB(32) LB(33) LB(34) LB(35) LB(36) LB(37) LB(38) LB(39)
#undef LB
  const float bgc = bias[gc];  // bias folded into accumulator init

  // ---- Elementwise-role constants: thread owns cell (r_e, c_e) ----
  const int r_e = tid >> 5;            // 0..15 row
  const int c_e = tid & 31;            // 0..31 h-col
  const int hcol = n_blk * 32 + c_e;   // [0, NH)
  const int grow = m_blk * 16 + r_e;   // [0, NB)
  float c_state = 0.0f;

  const int slot_base = m_blk * 32;

  // ---- Prefetch x tile for t=0 (16 rows x 256 = 512 16B chunks) ----
  bf16x8 xv = ((const bf16x8*)(xb + (m_blk * 16 + (tid >> 5)) * ND))[tid & 31];

  for (int t = 0; t < NT; ++t) {
    // ---- Stage A = [x_t | h_prev] (16 x 1280 bf16) into LDS ----
    {
      int r = tid >> 5, c = tid & 31;
      *(bf16x8*)(As + r * 1288 + c * 8) = xv;
      // h: agent-scope coherent 8B loads (LLC): 16 rows x 256 chunks
      const __bf16* hsrc = hbuf + (t & 1) * (NB * NH);
#pragma unroll
      for (int it = 0; it < 8; ++it) {
        int idx = tid + it * 512;
        int hr = idx >> 8, hc = idx & 255;
        unsigned long long v = __hip_atomic_load(
            (const unsigned long long*)(hsrc + (m_blk * 16 + hr) * NH) + hc,
            __ATOMIC_RELAXED, __HIP_MEMORY_SCOPE_AGENT);
        *(unsigned long long*)(As + hr * 1288 + 256 + hc * 4) = v;
      }
    }
    __syncthreads();

    // ---- MFMA: one 16x16 tile per wave, K=1280, two indep. acc chains ----
    floatx4 acc0 = {bgc, bgc, bgc, bgc};
    floatx4 acc1 = {0.f, 0.f, 0.f, 0.f};
    const __bf16* arow = As + n16 * 1288 + q * 8;
#define MF(ii, ACC)                                                        \
  {                                                                        \
    bf16x8 a = *(const bf16x8*)(arow + (ii) * 32);                         \
    ACC = __builtin_amdgcn_mfma_f32_16x16x32_bf16(a, B##ii, ACC, 0, 0, 0); \
  }
    MF(0, acc0) MF(1, acc1) MF(2, acc0) MF(3, acc1)
    MF(4, acc0) MF(5, acc1) MF(6, acc0) MF(7, acc1)
    MF(8, acc0) MF(9, acc1) MF(10, acc0) MF(11, acc1)
    MF(12, acc0) MF(13, acc1) MF(14, acc0) MF(15, acc1)
    MF(16, acc0) MF(17, acc1) MF(18, acc0) MF(19, acc1)
    MF(20, acc0) MF(21, acc1) MF(22, acc0) MF(23, acc1)
    MF(24, acc0) MF(25, acc1) MF(26, acc0) MF(27, acc1)
    MF(28, acc0) MF(29, acc1) MF(30, acc0) MF(31, acc1)
    MF(32, acc0) MF(33, acc1) MF(34, acc0) MF(35, acc1)
    MF(36, acc0) MF(37, acc1) MF(38, acc0) MF(39, acc1)
#undef MF
    floatx4 acc = acc0 + acc1;

    // ---- Spill gate tile to LDS: D[m=q*4+rr][n=n16] ----
    {
      int colL = g * 32 + half * 16 + n16;
#pragma unroll
      for (int rr = 0; rr < 4; ++rr) Gs[q * 4 + rr][colL] = acc[rr];
    }
    __syncthreads();  // gates ready (As fully consumed)

    // ---- LSTM cell (fp32, exact nonlinearities); bias already in gates ----
    {
      float xi = Gs[r_e][c_e];
      float xf = Gs[r_e][32 + c_e];
      float xg = Gs[r_e][64 + c_e];
      float xo = Gs[r_e][96 + c_e];
      float iv = sigmoidf_(xi);
      float fv = sigmoidf_(xf);
      float gv = softplusf_(xg);
      float ov = sigmoidf_(xo);
      c_state = fv * c_state + iv * gv;
      float hv = ov * softplusf_(c_state);
      Hso[r_e][c_e] = (__bf16)hv;
      if (t == NT - 1) hlast[grow * NH + hcol] = hv;
    }
    __syncthreads();  // Hso ready, Gs consumed

    if (t < NT - 1) {
      // ---- Prefetch next x tile (h-independent; completes during poll) ----
      xv = ((const bf16x8*)(xb + ((t + 1) * NB + m_blk * 16 + (tid >> 5)) * ND))[tid & 31];

      // ---- wave 0: publish h tile (16x32 bf16 = 128 x 8B, agent scope) ----
      if (tid < 64) {
        __bf16* hdst = hbuf + ((t + 1) & 1) * (NB * NH);
#pragma unroll
        for (int it = 0; it < 2; ++it) {
          int idx = tid + it * 64;          // 128 chunks of 8B
          int hr = idx >> 3, hc = idx & 7;  // row, 8B-chunk (32 cols = 8)
          unsigned long long v = *(const unsigned long long*)(&Hso[hr][hc * 4]);
          __hip_atomic_store(
              (unsigned long long*)(hdst + (m_blk * 16 + hr) * NH + n_blk * 32) + hc,
              v, __ATOMIC_RELAXED, __HIP_MEMORY_SCOPE_AGENT);
        }
      }
      if (tid == 0) {
        // release: same-wave h stores drain (vmcnt) before slot publish
        __hip_atomic_store(&slots[slot_base + n_blk], (unsigned)(t + 1),
                           __ATOMIC_RELEASE, __HIP_MEMORY_SCOPE_AGENT);
      }
      if (tid < 32) {  // wave 0 polls all 32 group slots
        unsigned tgt = (unsigned)(t + 1);
        while (__hip_atomic_load(&slots[slot_base + tid], __ATOMIC_RELAXED,
                                 __HIP_MEMORY_SCOPE_AGENT) < tgt) {
          __builtin_amdgcn_s_sleep(1);
        }
      }
      __syncthreads();  // all waves wait for barrier
    }
  }
}

// ---------------------------------------------------------------------------
// Kernel 3: projection head. 32 blocks x 128 thr; 4 batch rows per block.
// ---------------------------------------------------------------------------
__global__ __launch_bounds__(128) void proj_kernel(
    const float* __restrict__ hlast,
    const float* __restrict__ Wm, const float* __restrict__ bm,
    const float* __restrict__ Wv, const float* __restrict__ bv,
    const float* __restrict__ eps, float* __restrict__ out) {
  __shared__ float hs[4][NH];
  const int bb = blockIdx.x * 4;
  for (int idx = threadIdx.x; idx < 4 * NH; idx += 128)
    hs[idx >> 10][idx & (NH - 1)] = hlast[(bb + (idx >> 10)) * NH + (idx & (NH - 1))];
  __syncthreads();
  const int z = threadIdx.x;
  float am[4] = {0.f, 0.f, 0.f, 0.f};
  float av[4] = {0.f, 0.f, 0.f, 0.f};
#pragma unroll 8
  for (int k = 0; k < NH; ++k) {
    float wm = Wm[k * NZ + z];
    float wv = Wv[k * NZ + z];
#pragma unroll
    for (int r = 0; r < 4; ++r) {
      am[r] += hs[r][k] * wm;
      av[r] += hs[r][k] * wv;
    }
  }
#pragma unroll
  for (int r = 0; r < 4; ++r) {
    int b = bb + r;
    float mu = am[r] + bm[z];
    float lv = av[r] + bv[z];
    float zz = mu + eps[b * NZ + z] * expf(0.5f * lv);
    out[b * NZ + z] = mu;
    out[NB * NZ + b * NZ + z] = lv;
    out[2 * NB * NZ + b * NZ + z] = zz;
  }
}

// ---------------------------------------------------------------------------
extern "C" void kernel_launch(void* const* d_in, const int* in_sizes, int n_in,
                              void* d_out, int out_size, void* d_ws, size_t ws_size,
                              hipStream_t stream) {
  const float* x   = (const float*)d_in[0];
  const float* W   = (const float*)d_in[1];
  const float* U   = (const float*)d_in[2];
  const float* b   = (const float*)d_in[3];
  const float* Wm  = (const float*)d_in[4];
  const float* bm  = (const float*)d_in[5];
  const float* Wv  = (const float*)d_in[6];
  const float* bv  = (const float*)d_in[7];
  const float* eps = (const float*)d_in[8];

  // Workspace layout (needs ~34.6 MB):
  //   [0,       524288)   hbuf: 2 x B x H bf16
  //   [524288,  1048576)  hlast: B x H fp32
  //   [1048576, 1049600)  slots: 256 x u32 (padded to 4096)
  //   [1052672, +33.5MB)  xb: T x B x D bf16
  char* ws = (char*)d_ws;
  __bf16* hbuf = (__bf16*)ws;
  float* hlast = (float*)(ws + 524288);
  unsigned int* slots = (unsigned int*)(ws + 1048576);
  __bf16* xb = (__bf16*)(ws + 1048576 + 4096);

  hipMemsetAsync(hbuf, 0, NB * NH * sizeof(__bf16), stream);  // h_0 = 0
  hipMemsetAsync(slots, 0, 256 * sizeof(unsigned int), stream);

  convert_x_kernel<<<dim3((NB * NT * ND) / 4 / 256), dim3(256), 0, stream>>>(
      (const float4*)x, xb);

  void* args[] = {(void*)&xb, (void*)&W, (void*)&U, (void*)&b,
                  (void*)&hbuf, (void*)&hlast, (void*)&slots};
  hipLaunchCooperativeKernel(reinterpret_cast<void*>(lstm_persistent),
                             dim3(256), dim3(512), args, 0, stream);

  proj_kernel<<<dim3(32), dim3(128), 0, stream>>>(hlast, Wm, bm, Wv, bv, eps,
                                                  (float*)d_out);
}

// Round 7
// 3963.186 us; speedup vs baseline: 1.1368x; 1.1368x over previous
//
#include <hip/hip_runtime.h>
#include <hip/hip_bf16.h>
#include <stdint.h>

// Problem constants
#define NB 128    // batch
#define NT 512    // time steps
#define ND 256    // input dim
#define NH 1024   // hidden dim
#define NZ 128    // latent dim
#define NG 4096   // 4*NH gate width
#define NK 1280   // ND + NH combined K

typedef __attribute__((ext_vector_type(8))) __bf16 bf16x8;
typedef __attribute__((ext_vector_type(4))) __bf16 bf16x4;
typedef __attribute__((ext_vector_type(4))) float floatx4;

__device__ __forceinline__ float sigmoidf_(float x) { return 1.0f / (1.0f + expf(-x)); }
__device__ __forceinline__ float softplusf_(float x) {
  return (x > 0.0f) ? (x + log1pf(expf(-x))) : log1pf(expf(x));
}

// ---------------------------------------------------------------------------
// Kernel 1: convert x (B,T,D) fp32 -> xb (T,B,D) bf16
// ---------------------------------------------------------------------------
__global__ __launch_bounds__(256) void convert_x_kernel(
    const float4* __restrict__ x, __bf16* __restrict__ xb) {
  int i = blockIdx.x * 256 + threadIdx.x;   // [0, B*T*D/4)
  int d4 = i & 63;                          // float4 index within row of 256
  int bt = i >> 6;                          // b*512 + t
  int b = bt >> 9;
  int t = bt & 511;
  float4 v = x[i];
  bf16x4 o;
  o[0] = (__bf16)v.x; o[1] = (__bf16)v.y; o[2] = (__bf16)v.z; o[3] = (__bf16)v.w;
  *(bf16x4*)(xb + ((t * NB + b) * ND + d4 * 4)) = o;
}

// ---------------------------------------------------------------------------
// Kernel 2: persistent LSTM.
// Grid 256 WGs x 512 thr (1 WG/CU, cooperative). WG = (m_blk = blockIdx&7,
// n_blk = blockIdx>>3): batch rows [m_blk*16, +16), h-cols [n_blk*32, +32).
// R7: (1) A-fragment reuse: wave w owns K-half kh=w&1 and gate g=w>>1 with
// BOTH 16-col halves (40 frags = 160 regs, but only 20 A-reads/wave ->
// per-CU LDS A-traffic halves 320->160 KB/step). K-half partials reduced
// via Gs[2]. (2) h published directly from cell phase: pair-pack bf16x2 via
// shfl_xor, even lanes issue 4B agent stores (Hso LDS round-trip + wave0
// serial publish eliminated). (3) x(t+1) load issued at loop top (in flight
// during MFMA), written to As x-region right after MFMA-consumption sync.
// Evidence R2/R5/R6: weights reside in AGPRs regardless of array/named/LB
// (VGPR_Count 116-124, dur identical) — keep named for safety.
// Cross-WG exchange: agent-scope atomics only (no threadfence/L2 nukes).
// ---------------------------------------------------------------------------
__global__ __launch_bounds__(512, 1) void lstm_persistent(
    const __bf16* __restrict__ xb,    // (T, B, D) bf16
    const float* __restrict__ W,      // (D, 4H)
    const float* __restrict__ U,      // (H, 4H)
    const float* __restrict__ bias,   // (4H)
    __bf16* __restrict__ hbuf,        // 2 * B * H bf16 (double buffer)
    float* __restrict__ hlast,        // B * H fp32
    unsigned int* __restrict__ slots) // 256 barrier slots (8 groups x 32)
{
  const int tid = threadIdx.x;
  const int wg = blockIdx.x;
  const int m_blk = wg & 7;
  const int n_blk = wg >> 3;
  const int wave = tid >> 6;
  const int lane = tid & 63;
  const int q = lane >> 4;     // k-quad
  const int n16 = lane & 15;   // MFMA col within 16-col tile
  const int g = wave >> 1;     // gate index 0..3 (i,f,g,o)
  const int kh = wave & 1;     // K-half: [kh*640, +640)

  __shared__ __bf16 As[16 * 1288];   // A tile, rows padded 1280 -> 1288
  __shared__ float Gs[2][16][132];   // per-K-half gate partials, 128+4 pad

  // ---- Load persistent B fragments: 2 col-halves x 20 k-frags (named) ----
  const int gcA = g * NH + n_blk * 32 + n16;        // col-half 0
  const int gcB = gcA + 16;                          // col-half 1
#define LB(ii)                                                              \
  bf16x8 BA##ii, BB##ii;                                                    \
  {                                                                         \
    const int k0 = kh * 640 + (ii) * 32;                                    \
    const float* sA = (k0 < 256) ? (W + k0 * NG + gcA)                      \
                                 : (U + (k0 - 256) * NG + gcA);             \
    bf16x8 va, vb;                                                          \
    va[0] = (__bf16)sA[(q * 8 + 0) * NG]; vb[0] = (__bf16)sA[(q * 8 + 0) * NG + 16]; \
    va[1] = (__bf16)sA[(q * 8 + 1) * NG]; vb[1] = (__bf16)sA[(q * 8 + 1) * NG + 16]; \
    va[2] = (__bf16)sA[(q * 8 + 2) * NG]; vb[2] = (__bf16)sA[(q * 8 + 2) * NG + 16]; \
    va[3] = (__bf16)sA[(q * 8 + 3) * NG]; vb[3] = (__bf16)sA[(q * 8 + 3) * NG + 16]; \
    va[4] = (__bf16)sA[(q * 8 + 4) * NG]; vb[4] = (__bf16)sA[(q * 8 + 4) * NG + 16]; \
    va[5] = (__bf16)sA[(q * 8 + 5) * NG]; vb[5] = (__bf16)sA[(q * 8 + 5) * NG + 16]; \
    va[6] = (__bf16)sA[(q * 8 + 6) * NG]; vb[6] = (__bf16)sA[(q * 8 + 6) * NG + 16]; \
    va[7] = (__bf16)sA[(q * 8 + 7) * NG]; vb[7] = (__bf16)sA[(q * 8 + 7) * NG + 16]; \
    BA##ii = va; BB##ii = vb;                                               \
  }
  LB(0) LB(1) LB(2) LB(3) LB(4) LB(5) LB(6) LB(7) LB(8) LB(9)
  LB(10) LB(11) LB(12) LB(13) LB(14) LB(15) LB(16) LB(17) LB(18) LB(19)
#undef LB
  // Bias folded into kh==0 accumulators only (K-halves are summed later)
  const float bA = (kh == 0) ? bias[gcA] : 0.0f;
  const float bB = (kh == 0) ? bias[gcB] : 0.0f;

  // ---- Elementwise-role constants: thread owns cell (r_e, c_e) ----
  const int r_e = tid >> 5;            // 0..15 row
  const int c_e = tid & 31;            // 0..31 h-col
  const int hcol = n_blk * 32 + c_e;   // [0, NH)
  const int grow = m_blk * 16 + r_e;   // [0, NB)
  float c_state = 0.0f;

  const int slot_base = m_blk * 32;

  // ---- Stage x(0) into As x-region ----
  {
    int r = tid >> 5, c = tid & 31;
    bf16x8 x0 = ((const bf16x8*)(xb + (m_blk * 16 + r) * ND))[c];
    *(bf16x8*)(As + r * 1288 + c * 8) = x0;
  }

  for (int t = 0; t < NT; ++t) {
    // ---- Stage h_prev (16 rows x 256 8B-chunks) from LLC into As ----
    {
      const __bf16* hsrc = hbuf + (t & 1) * (NB * NH);
#pragma unroll
      for (int it = 0; it < 8; ++it) {
        int idx = tid + it * 512;
        int hr = idx >> 8, hc = idx & 255;
        unsigned long long v = __hip_atomic_load(
            (const unsigned long long*)(hsrc + (m_blk * 16 + hr) * NH) + hc,
            __ATOMIC_RELAXED, __HIP_MEMORY_SCOPE_AGENT);
        *(unsigned long long*)(As + hr * 1288 + 256 + hc * 4) = v;
      }
    }
    // ---- Issue x(t+1) load now; it flies during the MFMA phase ----
    bf16x8 xv;
    if (t < NT - 1) {
      xv = ((const bf16x8*)(xb + ((t + 1) * NB + m_blk * 16 + (tid >> 5)) * ND))[tid & 31];
    }
    __syncthreads();  // S1: A tile ready

    // ---- MFMA: 20 A-reads, each feeds 2 B-tiles; 4 indep. chains ----
    floatx4 aA0 = {bA, bA, bA, bA}, aA1 = {0.f, 0.f, 0.f, 0.f};
    floatx4 aB0 = {bB, bB, bB, bB}, aB1 = {0.f, 0.f, 0.f, 0.f};
    const __bf16* arow = As + n16 * 1288 + kh * 640 + q * 8;
#define MF(ii, AA, BBACC)                                                   \
  {                                                                         \
    bf16x8 a = *(const bf16x8*)(arow + (ii) * 32);                          \
    AA = __builtin_amdgcn_mfma_f32_16x16x32_bf16(a, BA##ii, AA, 0, 0, 0);   \
    BBACC = __builtin_amdgcn_mfma_f32_16x16x32_bf16(a, BB##ii, BBACC, 0, 0, 0); \
  }
    MF(0, aA0, aB0) MF(1, aA1, aB1) MF(2, aA0, aB0) MF(3, aA1, aB1)
    MF(4, aA0, aB0) MF(5, aA1, aB1) MF(6, aA0, aB0) MF(7, aA1, aB1)
    MF(8, aA0, aB0) MF(9, aA1, aB1) MF(10, aA0, aB0) MF(11, aA1, aB1)
    MF(12, aA0, aB0) MF(13, aA1, aB1) MF(14, aA0, aB0) MF(15, aA1, aB1)
    MF(16, aA0, aB0) MF(17, aA1, aB1) MF(18, aA0, aB0) MF(19, aA1, aB1)
#undef MF
    floatx4 accA = aA0 + aA1;  // col-half 0 (cols n16)
    floatx4 accB = aB0 + aB1;  // col-half 1 (cols 16+n16)

    // ---- Spill partial gates: Gs[kh][row][g*32 + half*16 + n16] ----
#pragma unroll
    for (int rr = 0; rr < 4; ++rr) {
      Gs[kh][q * 4 + rr][g * 32 + n16] = accA[rr];
      Gs[kh][q * 4 + rr][g * 32 + 16 + n16] = accB[rr];
    }
    __syncthreads();  // S2: gates ready, As fully consumed

    // ---- Write x(t+1) into As x-region (overlaps cell + barrier) ----
    if (t < NT - 1) {
      *(bf16x8*)(As + (tid >> 5) * 1288 + (tid & 31) * 8) = xv;
    }

    // ---- LSTM cell (fp32): sum K-halves; bias already in ----
    {
      float xi = Gs[0][r_e][c_e] + Gs[1][r_e][c_e];
      float xf = Gs[0][r_e][32 + c_e] + Gs[1][r_e][32 + c_e];
      float xg = Gs[0][r_e][64 + c_e] + Gs[1][r_e][64 + c_e];
      float xo = Gs[0][r_e][96 + c_e] + Gs[1][r_e][96 + c_e];
      float iv = sigmoidf_(xi);
      float fv = sigmoidf_(xf);
      float gv = softplusf_(xg);
      float ov = sigmoidf_(xo);
      c_state = fv * c_state + iv * gv;
      float hv = ov * softplusf_(c_state);
      if (t == NT - 1) {
        hlast[grow * NH + hcol] = hv;
      } else {
        // ---- Direct h publish: pair-pack via shfl, even lanes 4B store ----
        float hv_n = __shfl_xor(hv, 1);  // partner col (c_e^1)
        if ((c_e & 1) == 0) {
          __hip_bfloat162 pk;
          pk.x = (__hip_bfloat16)hv; pk.y = (__hip_bfloat16)hv_n;
          unsigned int pv = *(unsigned int*)&pk;
          unsigned int* dst = (unsigned int*)(hbuf + ((t + 1) & 1) * (NB * NH)
                                              + grow * NH + hcol);
          __hip_atomic_store(dst, pv, __ATOMIC_RELAXED, __HIP_MEMORY_SCOPE_AGENT);
        }
      }
    }

    if (t < NT - 1) {
      __syncthreads();  // S3: every wave drains vmcnt -> all h stores done
      if (tid == 0) {
        __hip_atomic_store(&slots[slot_base + n_blk], (unsigned)(t + 1),
                           __ATOMIC_RELEASE, __HIP_MEMORY_SCOPE_AGENT);
      }
      if (tid < 32) {  // wave 0 polls all 32 group slots
        unsigned tgt = (unsigned)(t + 1);
        while (__hip_atomic_load(&slots[slot_base + tid], __ATOMIC_RELAXED,
                                 __HIP_MEMORY_SCOPE_AGENT) < tgt) {
          __builtin_amdgcn_s_sleep(1);
        }
      }
      __syncthreads();  // S4: barrier passed
    }
  }
}

// ---------------------------------------------------------------------------
// Kernel 3: projection head. 32 blocks x 128 thr; 4 batch rows per block.
// ---------------------------------------------------------------------------
__global__ __launch_bounds__(128) void proj_kernel(
    const float* __restrict__ hlast,
    const float* __restrict__ Wm, const float* __restrict__ bm,
    const float* __restrict__ Wv, const float* __restrict__ bv,
    const float* __restrict__ eps, float* __restrict__ out) {
  __shared__ float hs[4][NH];
  const int bb = blockIdx.x * 4;
  for (int idx = threadIdx.x; idx < 4 * NH; idx += 128)
    hs[idx >> 10][idx & (NH - 1)] = hlast[(bb + (idx >> 10)) * NH + (idx & (NH - 1))];
  __syncthreads();
  const int z = threadIdx.x;
  float am[4] = {0.f, 0.f, 0.f, 0.f};
  float av[4] = {0.f, 0.f, 0.f, 0.f};
#pragma unroll 8
  for (int k = 0; k < NH; ++k) {
    float wm = Wm[k * NZ + z];
    float wv = Wv[k * NZ + z];
#pragma unroll
    for (int r = 0; r < 4; ++r) {
      am[r] += hs[r][k] * wm;
      av[r] += hs[r][k] * wv;
    }
  }
#pragma unroll
  for (int r = 0; r < 4; ++r) {
    int b = bb + r;
    float mu = am[r] + bm[z];
    float lv = av[r] + bv[z];
    float zz = mu + eps[b * NZ + z] * expf(0.5f * lv);
    out[b * NZ + z] = mu;
    out[NB * NZ + b * NZ + z] = lv;
    out[2 * NB * NZ + b * NZ + z] = zz;
  }
}

// ---------------------------------------------------------------------------
extern "C" void kernel_launch(void* const* d_in, const int* in_sizes, int n_in,
                              void* d_out, int out_size, void* d_ws, size_t ws_size,
                              hipStream_t stream) {
  const float* x   = (const float*)d_in[0];
  const float* W   = (const float*)d_in[1];
  const float* U   = (const float*)d_in[2];
  const float* b   = (const float*)d_in[3];
  const float* Wm  = (const float*)d_in[4];
  const float* bm  = (const float*)d_in[5];
  const float* Wv  = (const float*)d_in[6];
  const float* bv  = (const float*)d_in[7];
  const float* eps = (const float*)d_in[8];

  // Workspace layout (needs ~34.6 MB):
  //   [0,       524288)   hbuf: 2 x B x H bf16
  //   [524288,  1048576)  hlast: B x H fp32
  //   [1048576, 1049600)  slots: 256 x u32 (padded to 4096)
  //   [1052672, +33.5MB)  xb: T x B x D bf16
  char* ws = (char*)d_ws;
  __bf16* hbuf = (__bf16*)ws;
  float* hlast = (float*)(ws + 524288);
  unsigned int* slots = (unsigned int*)(ws + 1048576);
  __bf16* xb = (__bf16*)(ws + 1048576 + 4096);

  hipMemsetAsync(hbuf, 0, NB * NH * sizeof(__bf16), stream);  // h_0 = 0
  hipMemsetAsync(slots, 0, 256 * sizeof(unsigned int), stream);

  convert_x_kernel<<<dim3((NB * NT * ND) / 4 / 256), dim3(256), 0, stream>>>(
      (const float4*)x, xb);

  void* args[] = {(void*)&xb, (void*)&W, (void*)&U, (void*)&b,
                  (void*)&hbuf, (void*)&hlast, (void*)&slots};
  hipLaunchCooperativeKernel(reinterpret_cast<void*>(lstm_persistent),
                             dim3(256), dim3(512), args, 0, stream);

  proj_kernel<<<dim3(32), dim3(128), 0, stream>>>(hlast, Wm, bm, Wv, bv, eps,
                                                  (float*)d_out);
}

// Round 8
// 3353.671 us; speedup vs baseline: 1.3434x; 1.1817x over previous
//
#include <hip/hip_runtime.h>
#include <hip/hip_bf16.h>
#include <stdint.h>

// Problem constants
#define NB 128    // batch
#define NT 512    // time steps
#define ND 256    // input dim
#define NH 1024   // hidden dim
#define NZ 128    // latent dim
#define NG 4096   // 4*NH gate width
#define NK 1280   // ND + NH combined K

typedef __attribute__((ext_vector_type(8))) __bf16 bf16x8;
typedef __attribute__((ext_vector_type(4))) __bf16 bf16x4;
typedef __attribute__((ext_vector_type(4))) float floatx4;

// Fast native transcendentals (v_exp_f32 / v_log_f32 / v_rcp_f32).
// Max rel err ~1e-6 -- absmax threshold is 0.171, current slack ~5x.
__device__ __forceinline__ float fsigmoid_(float x) {
  return __fdividef(1.0f, 1.0f + __expf(-x));
}
__device__ __forceinline__ float fsoftplus_(float x) {
  return fmaxf(x, 0.0f) + __logf(1.0f + __expf(-fabsf(x)));
}

// ---------------------------------------------------------------------------
// Kernel 1: convert x (B,T,D) fp32 -> xb (T,B,D) bf16
// ---------------------------------------------------------------------------
__global__ __launch_bounds__(256) void convert_x_kernel(
    const float4* __restrict__ x, __bf16* __restrict__ xb) {
  int i = blockIdx.x * 256 + threadIdx.x;   // [0, B*T*D/4)
  int d4 = i & 63;                          // float4 index within row of 256
  int bt = i >> 6;                          // b*512 + t
  int b = bt >> 9;
  int t = bt & 511;
  float4 v = x[i];
  bf16x4 o;
  o[0] = (__bf16)v.x; o[1] = (__bf16)v.y; o[2] = (__bf16)v.z; o[3] = (__bf16)v.w;
  *(bf16x4*)(xb + ((t * NB + b) * ND + d4 * 4)) = o;
}

// ---------------------------------------------------------------------------
// Kernel 2: persistent LSTM.
// Grid 256 WGs x 512 thr (1 WG/CU, cooperative). WG = (m_blk = blockIdx&7,
// n_blk = blockIdx>>3): batch rows [m_blk*16, +16), h-cols [n_blk*32, +32).
// Wave w: gate g = w>>1, K-half kh = w&1. R8 K-split: wave owns
// x[kh*128,+128) (4 frags) + h[kh*512,+512) (16 frags); the 4 x-MFMAs for
// step t+1 execute DURING the barrier wait (between release and poll),
// hiding them + acc init off the critical path. A-frag reuse across both
// 16-col B-tiles (R7) kept. Fast native exp/log/rcp in the cell (R8).
// h publish packed to 8B via 2x shfl_xor (R8; restores write-combining).
// Cross-WG exchange: agent-scope atomics only (no fences/L2 nukes).
// ---------------------------------------------------------------------------
__global__ __launch_bounds__(512, 1) void lstm_persistent(
    const __bf16* __restrict__ xb,    // (T, B, D) bf16
    const float* __restrict__ W,      // (D, 4H)
    const float* __restrict__ U,      // (H, 4H)
    const float* __restrict__ bias,   // (4H)
    __bf16* __restrict__ hbuf,        // 2 * B * H bf16 (double buffer)
    float* __restrict__ hlast,        // B * H fp32
    unsigned int* __restrict__ slots) // 256 barrier slots (8 groups x 32)
{
  const int tid = threadIdx.x;
  const int wg = blockIdx.x;
  const int m_blk = wg & 7;
  const int n_blk = wg >> 3;
  const int wave = tid >> 6;
  const int lane = tid & 63;
  const int q = lane >> 4;     // k-quad
  const int n16 = lane & 15;   // MFMA col within 16-col tile
  const int g = wave >> 1;     // gate index 0..3 (i,f,g,o)
  const int kh = wave & 1;     // K-half

  __shared__ __bf16 As[16 * 1288];   // A tile: x [0,256) + h [256,1280), pad
  __shared__ float Gs[2][16][132];   // per-K-half gate partials, 128+4 pad

  // ---- Persistent B fragments: frag ii<4 = x-part W rows kh*128+ii*32;
  //      ii>=4 = h-part U rows kh*512+(ii-4)*32. 2 col-halves each. ----
  const int gcA = g * NH + n_blk * 32 + n16;   // col-half 0
  const int gcB = gcA + 16;                    // col-half 1
#define LB(ii)                                                              \
  bf16x8 BA##ii, BB##ii;                                                    \
  {                                                                         \
    const int k0 = ((ii) < 4) ? (kh * 128 + (ii) * 32)                      \
                              : (256 + kh * 512 + ((ii) - 4) * 32);         \
    const float* sA = (k0 < 256) ? (W + k0 * NG + gcA)                      \
                                 : (U + (k0 - 256) * NG + gcA);             \
    bf16x8 va, vb;                                                          \
    va[0] = (__bf16)sA[(q * 8 + 0) * NG]; vb[0] = (__bf16)sA[(q * 8 + 0) * NG + 16]; \
    va[1] = (__bf16)sA[(q * 8 + 1) * NG]; vb[1] = (__bf16)sA[(q * 8 + 1) * NG + 16]; \
    va[2] = (__bf16)sA[(q * 8 + 2) * NG]; vb[2] = (__bf16)sA[(q * 8 + 2) * NG + 16]; \
    va[3] = (__bf16)sA[(q * 8 + 3) * NG]; vb[3] = (__bf16)sA[(q * 8 + 3) * NG + 16]; \
    va[4] = (__bf16)sA[(q * 8 + 4) * NG]; vb[4] = (__bf16)sA[(q * 8 + 4) * NG + 16]; \
    va[5] = (__bf16)sA[(q * 8 + 5) * NG]; vb[5] = (__bf16)sA[(q * 8 + 5) * NG + 16]; \
    va[6] = (__bf16)sA[(q * 8 + 6) * NG]; vb[6] = (__bf16)sA[(q * 8 + 6) * NG + 16]; \
    va[7] = (__bf16)sA[(q * 8 + 7) * NG]; vb[7] = (__bf16)sA[(q * 8 + 7) * NG + 16]; \
    BA##ii = va; BB##ii = vb;                                               \
  }
  LB(0) LB(1) LB(2) LB(3) LB(4) LB(5) LB(6) LB(7) LB(8) LB(9)
  LB(10) LB(11) LB(12) LB(13) LB(14) LB(15) LB(16) LB(17) LB(18) LB(19)
#undef LB
  // Bias folded into kh==0 accumulators only (K-halves summed later)
  const float bA = (kh == 0) ? bias[gcA] : 0.0f;
  const float bB = (kh == 0) ? bias[gcB] : 0.0f;

  // ---- Elementwise-role constants ----
  const int r_e = tid >> 5;            // 0..15 row
  const int c_e = tid & 31;            // 0..31 h-col
  const int hcol = n_blk * 32 + c_e;   // [0, NH)
  const int grow = m_blk * 16 + r_e;   // [0, NB)
  float c_state = 0.0f;

  const int slot_base = m_blk * 32;

#define MFMA_(a, b, acc) __builtin_amdgcn_mfma_f32_16x16x32_bf16(a, b, acc, 0, 0, 0)

  floatx4 aA0, aA1, aB0, aB1;
  // acc init + 4 x-part MFMAs (reads As x-region; caller ensures synced)
#define XPHASE()                                                            \
  {                                                                         \
    aA0 = (floatx4){bA, bA, bA, bA}; aA1 = (floatx4){0.f, 0.f, 0.f, 0.f};   \
    aB0 = (floatx4){bB, bB, bB, bB}; aB1 = (floatx4){0.f, 0.f, 0.f, 0.f};   \
    const __bf16* xr = As + n16 * 1288 + kh * 128 + q * 8;                  \
    bf16x8 a0 = *(const bf16x8*)(xr);                                       \
    bf16x8 a1 = *(const bf16x8*)(xr + 32);                                  \
    bf16x8 a2 = *(const bf16x8*)(xr + 64);                                  \
    bf16x8 a3 = *(const bf16x8*)(xr + 96);                                  \
    aA0 = MFMA_(a0, BA0, aA0); aB0 = MFMA_(a0, BB0, aB0);                   \
    aA1 = MFMA_(a1, BA1, aA1); aB1 = MFMA_(a1, BB1, aB1);                   \
    aA0 = MFMA_(a2, BA2, aA0); aB0 = MFMA_(a2, BB2, aB0);                   \
    aA1 = MFMA_(a3, BA3, aA1); aB1 = MFMA_(a3, BB3, aB1);                   \
  }

  // ---- Prologue: stage x(0) + h(0), then x-phase for t=0 ----
  {
    int r = tid >> 5, c = tid & 31;
    bf16x8 x0 = ((const bf16x8*)(xb + (m_blk * 16 + r) * ND))[c];
    *(bf16x8*)(As + r * 1288 + c * 8) = x0;
    const __bf16* hsrc = hbuf;  // zeros
#pragma unroll
    for (int it = 0; it < 8; ++it) {
      int idx = tid + it * 512;
      int hr = idx >> 8, hc = idx & 255;
      unsigned long long v = __hip_atomic_load(
          (const unsigned long long*)(hsrc + (m_blk * 16 + hr) * NH) + hc,
          __ATOMIC_RELAXED, __HIP_MEMORY_SCOPE_AGENT);
      *(unsigned long long*)(As + hr * 1288 + 256 + hc * 4) = v;
    }
  }
  __syncthreads();  // S1: A(0) staged
  XPHASE()

  for (int t = 0; t < NT; ++t) {
    // ---- Issue x(t+1) load; flies during the h-MFMA phase ----
    bf16x8 xv;
    if (t < NT - 1) {
      xv = ((const bf16x8*)(xb + ((t + 1) * NB + m_blk * 16 + (tid >> 5)) * ND))[tid & 31];
    }

    // ---- h-part MFMAs: 16 frags, each A-read feeds 2 B-tiles ----
    {
      const __bf16* hrw = As + n16 * 1288 + 256 + kh * 512 + q * 8;
#define MF(ii, AA, BBACC)                                                   \
  {                                                                         \
    bf16x8 a = *(const bf16x8*)(hrw + ((ii) - 4) * 32);                     \
    AA = MFMA_(a, BA##ii, AA);                                              \
    BBACC = MFMA_(a, BB##ii, BBACC);                                        \
  }
      MF(4, aA0, aB0) MF(5, aA1, aB1) MF(6, aA0, aB0) MF(7, aA1, aB1)
      MF(8, aA0, aB0) MF(9, aA1, aB1) MF(10, aA0, aB0) MF(11, aA1, aB1)
      MF(12, aA0, aB0) MF(13, aA1, aB1) MF(14, aA0, aB0) MF(15, aA1, aB1)
      MF(16, aA0, aB0) MF(17, aA1, aB1) MF(18, aA0, aB0) MF(19, aA1, aB1)
#undef MF
    }
    floatx4 accA = aA0 + aA1;  // col-half 0 (cols n16)
    floatx4 accB = aB0 + aB1;  // col-half 1 (cols 16+n16)

    // ---- Spill partial gates: Gs[kh][row][g*32 + {0,16} + n16] ----
#pragma unroll
    for (int rr = 0; rr < 4; ++rr) {
      Gs[kh][q * 4 + rr][g * 32 + n16] = accA[rr];
      Gs[kh][q * 4 + rr][g * 32 + 16 + n16] = accB[rr];
    }
    __syncthreads();  // S2: gates ready, As fully consumed

    // ---- Write x(t+1) into As x-region (consumed by XPHASE after S3) ----
    if (t < NT - 1) {
      *(bf16x8*)(As + (tid >> 5) * 1288 + (tid & 31) * 8) = xv;
    }

    // ---- LSTM cell (fp32, fast native exp/log/rcp) ----
    {
      float xi = Gs[0][r_e][c_e] + Gs[1][r_e][c_e];
      float xf = Gs[0][r_e][32 + c_e] + Gs[1][r_e][32 + c_e];
      float xg = Gs[0][r_e][64 + c_e] + Gs[1][r_e][64 + c_e];
      float xo = Gs[0][r_e][96 + c_e] + Gs[1][r_e][96 + c_e];
      float iv = fsigmoid_(xi);
      float fv = fsigmoid_(xf);
      float gv = fsoftplus_(xg);
      float ov = fsigmoid_(xo);
      c_state = fv * c_state + iv * gv;
      float hv = ov * fsoftplus_(c_state);
      if (t == NT - 1) {
        hlast[grow * NH + hcol] = hv;
      } else {
        // ---- 8B packed publish: 2x shfl_xor, lanes c_e%4==0 store ----
        float hn1 = __shfl_xor(hv, 1);
        __hip_bfloat162 pk;
        pk.x = (__hip_bfloat16)hv; pk.y = (__hip_bfloat16)hn1;
        unsigned int p = *(unsigned int*)&pk;
        unsigned int po = (unsigned int)__shfl_xor((int)p, 2);
        if ((c_e & 3) == 0) {
          unsigned long long v = ((unsigned long long)po << 32) | p;
          __hip_atomic_store(
              (unsigned long long*)(hbuf + ((t + 1) & 1) * (NB * NH)
                                    + grow * NH + hcol),
              v, __ATOMIC_RELAXED, __HIP_MEMORY_SCOPE_AGENT);
        }
      }
    }

    if (t < NT - 1) {
      __syncthreads();  // S3: publishes drained (vmcnt0/wave), x-region visible
      if (tid == 0) {
        __hip_atomic_store(&slots[slot_base + n_blk], (unsigned)(t + 1),
                           __ATOMIC_RELEASE, __HIP_MEMORY_SCOPE_AGENT);
      }
      // ---- Hidden work while the group converges: x-GEMM for t+1 ----
      XPHASE()
      if (tid < 32) {  // wave 0 polls all 32 group slots
        unsigned tgt = (unsigned)(t + 1);
        while (__hip_atomic_load(&slots[slot_base + tid], __ATOMIC_RELAXED,
                                 __HIP_MEMORY_SCOPE_AGENT) < tgt) {
          __builtin_amdgcn_s_sleep(1);
        }
      }
      __syncthreads();  // S4: barrier passed

      // ---- Gather h(t+1) from LLC into As h-region ----
      {
        const __bf16* hsrc = hbuf + ((t + 1) & 1) * (NB * NH);
#pragma unroll
        for (int it = 0; it < 8; ++it) {
          int idx = tid + it * 512;
          int hr = idx >> 8, hc = idx & 255;
          unsigned long long v = __hip_atomic_load(
              (const unsigned long long*)(hsrc + (m_blk * 16 + hr) * NH) + hc,
              __ATOMIC_RELAXED, __HIP_MEMORY_SCOPE_AGENT);
          *(unsigned long long*)(As + hr * 1288 + 256 + hc * 4) = v;
        }
      }
      __syncthreads();  // S1': h staged for next iteration
    }
  }
#undef XPHASE
#undef MFMA_
}

// ---------------------------------------------------------------------------
// Kernel 3: projection head. 32 blocks x 128 thr; 4 batch rows per block.
// ---------------------------------------------------------------------------
__global__ __launch_bounds__(128) void proj_kernel(
    const float* __restrict__ hlast,
    const float* __restrict__ Wm, const float* __restrict__ bm,
    const float* __restrict__ Wv, const float* __restrict__ bv,
    const float* __restrict__ eps, float* __restrict__ out) {
  __shared__ float hs[4][NH];
  const int bb = blockIdx.x * 4;
  for (int idx = threadIdx.x; idx < 4 * NH; idx += 128)
    hs[idx >> 10][idx & (NH - 1)] = hlast[(bb + (idx >> 10)) * NH + (idx & (NH - 1))];
  __syncthreads();
  const int z = threadIdx.x;
  float am[4] = {0.f, 0.f, 0.f, 0.f};
  float av[4] = {0.f, 0.f, 0.f, 0.f};
#pragma unroll 8
  for (int k = 0; k < NH; ++k) {
    float wm = Wm[k * NZ + z];
    float wv = Wv[k * NZ + z];
#pragma unroll
    for (int r = 0; r < 4; ++r) {
      am[r] += hs[r][k] * wm;
      av[r] += hs[r][k] * wv;
    }
  }
#pragma unroll
  for (int r = 0; r < 4; ++r) {
    int b = bb + r;
    float mu = am[r] + bm[z];
    float lv = av[r] + bv[z];
    float zz = mu + eps[b * NZ + z] * expf(0.5f * lv);
    out[b * NZ + z] = mu;
    out[NB * NZ + b * NZ + z] = lv;
    out[2 * NB * NZ + b * NZ + z] = zz;
  }
}

// ---------------------------------------------------------------------------
extern "C" void kernel_launch(void* const* d_in, const int* in_sizes, int n_in,
                              void* d_out, int out_size, void* d_ws, size_t ws_size,
                              hipStream_t stream) {
  const float* x   = (const float*)d_in[0];
  const float* W   = (const float*)d_in[1];
  const float* U   = (const float*)d_in[2];
  const float* b   = (const float*)d_in[3];
  const float* Wm  = (const float*)d_in[4];
  const float* bm  = (const float*)d_in[5];
  const float* Wv  = (const float*)d_in[6];
  const float* bv  = (const float*)d_in[7];
  const float* eps = (const float*)d_in[8];

  // Workspace layout (needs ~34.6 MB):
  //   [0,       524288)   hbuf: 2 x B x H bf16
  //   [524288,  1048576)  hlast: B x H fp32
  //   [1048576, 1049600)  slots: 256 x u32 (padded to 4096)
  //   [1052672, +33.5MB)  xb: T x B x D bf16
  char* ws = (char*)d_ws;
  __bf16* hbuf = (__bf16*)ws;
  float* hlast = (float*)(ws + 524288);
  unsigned int* slots = (unsigned int*)(ws + 1048576);
  __bf16* xb = (__bf16*)(ws + 1048576 + 4096);

  hipMemsetAsync(hbuf, 0, NB * NH * sizeof(__bf16), stream);  // h_0 = 0
  hipMemsetAsync(slots, 0, 256 * sizeof(unsigned int), stream);

  convert_x_kernel<<<dim3((NB * NT * ND) / 4 / 256), dim3(256), 0, stream>>>(
      (const float4*)x, xb);

  void* args[] = {(void*)&xb, (void*)&W, (void*)&U, (void*)&b,
                  (void*)&hbuf, (void*)&hlast, (void*)&slots};
  hipLaunchCooperativeKernel(reinterpret_cast<void*>(lstm_persistent),
                             dim3(256), dim3(512), args, 0, stream);

  proj_kernel<<<dim3(32), dim3(128), 0, stream>>>(hlast, Wm, bm, Wv, bv, eps,
                                                  (float*)d_out);
}

// Round 9
// 3342.843 us; speedup vs baseline: 1.3477x; 1.0032x over previous
//
#include <hip/hip_runtime.h>
#include <hip/hip_bf16.h>
#include <stdint.h>

// Problem constants
#define NB 128    // batch
#define NT 512    // time steps
#define ND 256    // input dim
#define NH 1024   // hidden dim
#define NZ 128    // latent dim
#define NG 4096   // 4*NH gate width

typedef __attribute__((ext_vector_type(8))) __bf16 bf16x8;
typedef __attribute__((ext_vector_type(4))) __bf16 bf16x4;
typedef __attribute__((ext_vector_type(4))) float floatx4;

// Fast native transcendentals (v_exp_f32 / v_log_f32 / v_rcp_f32).
__device__ __forceinline__ float fsigmoid_(float x) {
  return __fdividef(1.0f, 1.0f + __expf(-x));
}
__device__ __forceinline__ float fsoftplus_(float x) {
  return fmaxf(x, 0.0f) + __logf(1.0f + __expf(-fabsf(x)));
}

// B-fragment loader: 8 fp32 rows (stride NG) -> bf16x8
__device__ __forceinline__ bf16x8 load_bfrag(const float* s) {
  bf16x8 v;
#pragma unroll
  for (int jj = 0; jj < 8; ++jj) v[jj] = (__bf16)s[jj * NG];
  return v;
}

// ---------------------------------------------------------------------------
// Kernel 1: convert x (B,T,D) fp32 -> xb (T,B,D) bf16
// ---------------------------------------------------------------------------
__global__ __launch_bounds__(256) void convert_x_kernel(
    const float4* __restrict__ x, __bf16* __restrict__ xb) {
  int i = blockIdx.x * 256 + threadIdx.x;
  int d4 = i & 63;
  int bt = i >> 6;
  int b = bt >> 9;
  int t = bt & 511;
  float4 v = x[i];
  bf16x4 o;
  o[0] = (__bf16)v.x; o[1] = (__bf16)v.y; o[2] = (__bf16)v.z; o[3] = (__bf16)v.w;
  *(bf16x4*)(xb + ((t * NB + b) * ND + d4 * 4)) = o;
}

// ---------------------------------------------------------------------------
// Kernel 2: persistent LSTM.
// Grid 256 WGs x 512 thr (1 WG/CU, cooperative). WG = (m_blk = blockIdx&7,
// n_blk = blockIdx>>3): batch rows [m_blk*16,+16), h-cols [n_blk*32,+32).
// R9 K-partition: wave w owns a UNIQUE K-eighth for ALL 4 gates:
//   x-rows [w*32,+32) (8 B-frags: 4 gates x 2 col-halves) and
//   h-rows [w*128,+128) (32 B-frags: 4 slices x 8) -> 160 VGPRs total.
// Wave w polls only ITS 4 source slots (WGs w*4..w*4+3) and loads its h
// A-fragments DIRECTLY LLC->VGPR (two 8B agent loads/lane) — no LDS h
// staging, no S4/S1' syncs; gather + 32/40 MFMAs overlap the straggler
// wait. 8-wave gate partials reduce through Gs[8][16][132].
// t=0 needs no poll (slots start 0, hbuf half 0 zeroed -> h-MFMAs add 0).
// Cell: fast native exp/log (R8). Publish: 8B packed agent stores (R8).
// Syncs/step: S2 (gates ready) + S3 (publish drained) only.
// ---------------------------------------------------------------------------
__global__ __launch_bounds__(512, 1) void lstm_persistent(
    const __bf16* __restrict__ xb,    // (T, B, D) bf16
    const float* __restrict__ W,      // (D, 4H)
    const float* __restrict__ U,      // (H, 4H)
    const float* __restrict__ bias,   // (4H)
    __bf16* __restrict__ hbuf,        // 2 * B * H bf16 (double buffer)
    float* __restrict__ hlast,        // B * H fp32
    unsigned int* __restrict__ slots) // 256 barrier slots (8 groups x 32)
{
  const int tid = threadIdx.x;
  const int wg = blockIdx.x;
  const int m_blk = wg & 7;
  const int n_blk = wg >> 3;
  const int wave = tid >> 6;
  const int lane = tid & 63;
  const int q = lane >> 4;     // k-quad
  const int n16 = lane & 15;   // MFMA col within 16-col tile

  __shared__ __bf16 As[16 * 264];    // x tile only: 16 x 256 (+8 pad)
  __shared__ float Gs[8][16][132];   // per-wave gate partials, 128+4 pad

  // ---- Gate-column bases (4 gates x 2 col-halves) ----
  const int nb = n_blk * 32 + n16;
  const int c00 = nb,            c01 = nb + 16;
  const int c10 = NH + nb,       c11 = NH + nb + 16;
  const int c20 = 2 * NH + nb,   c21 = 2 * NH + nb + 16;
  const int c30 = 3 * NH + nb,   c31 = 3 * NH + nb + 16;

  // ---- Persistent B fragments ----
  // x-part: W rows [wave*32,+32): 8 frags
  const float* Wb = W + (wave * 32 + q * 8) * NG;
  bf16x8 BX00 = load_bfrag(Wb + c00), BX01 = load_bfrag(Wb + c01);
  bf16x8 BX10 = load_bfrag(Wb + c10), BX11 = load_bfrag(Wb + c11);
  bf16x8 BX20 = load_bfrag(Wb + c20), BX21 = load_bfrag(Wb + c21);
  bf16x8 BX30 = load_bfrag(Wb + c30), BX31 = load_bfrag(Wb + c31);
  // h-part: U rows [wave*128,+128), 4 slices x 8: 32 frags
  const float* Ub = U + (wave * 128 + q * 8) * NG;
#define DECL_J(J)                                                       \
  bf16x8 BH00##J = load_bfrag(Ub + (J) * 32 * NG + c00);                \
  bf16x8 BH01##J = load_bfrag(Ub + (J) * 32 * NG + c01);                \
  bf16x8 BH10##J = load_bfrag(Ub + (J) * 32 * NG + c10);                \
  bf16x8 BH11##J = load_bfrag(Ub + (J) * 32 * NG + c11);                \
  bf16x8 BH20##J = load_bfrag(Ub + (J) * 32 * NG + c20);                \
  bf16x8 BH21##J = load_bfrag(Ub + (J) * 32 * NG + c21);                \
  bf16x8 BH30##J = load_bfrag(Ub + (J) * 32 * NG + c30);                \
  bf16x8 BH31##J = load_bfrag(Ub + (J) * 32 * NG + c31);
  DECL_J(0) DECL_J(1) DECL_J(2) DECL_J(3)
#undef DECL_J

  // Bias folded into wave 0's accumulator init only (partials are summed)
  const float b00 = (wave == 0) ? bias[c00] : 0.f;
  const float b01 = (wave == 0) ? bias[c01] : 0.f;
  const float b10 = (wave == 0) ? bias[c10] : 0.f;
  const float b11 = (wave == 0) ? bias[c11] : 0.f;
  const float b20 = (wave == 0) ? bias[c20] : 0.f;
  const float b21 = (wave == 0) ? bias[c21] : 0.f;
  const float b30 = (wave == 0) ? bias[c30] : 0.f;
  const float b31 = (wave == 0) ? bias[c31] : 0.f;

  // ---- Elementwise-role constants ----
  const int r_e = tid >> 5;            // 0..15 row
  const int c_e = tid & 31;            // 0..31 h-col
  const int hcol = n_blk * 32 + c_e;
  const int grow = m_blk * 16 + r_e;
  float c_state = 0.0f;

  const int slot_base = m_blk * 32;
  const int sidx = slot_base + (wave << 2) + (lane & 3);  // my 4 source slots

#define MFMA_(a, b, acc) __builtin_amdgcn_mfma_f32_16x16x32_bf16(a, b, acc, 0, 0, 0)
#define AL(p) __hip_atomic_load(p, __ATOMIC_RELAXED, __HIP_MEMORY_SCOPE_AGENT)

  floatx4 AC00, AC01, AC10, AC11, AC20, AC21, AC30, AC31;
  // acc init (bias) + 8 x-part MFMAs; reads As x-region
#define XPHASE()                                                        \
  {                                                                     \
    const __bf16* xr = As + n16 * 264 + wave * 32 + q * 8;              \
    bf16x8 a = *(const bf16x8*)xr;                                      \
    AC00 = (floatx4){b00, b00, b00, b00}; AC01 = (floatx4){b01, b01, b01, b01}; \
    AC10 = (floatx4){b10, b10, b10, b10}; AC11 = (floatx4){b11, b11, b11, b11}; \
    AC20 = (floatx4){b20, b20, b20, b20}; AC21 = (floatx4){b21, b21, b21, b21}; \
    AC30 = (floatx4){b30, b30, b30, b30}; AC31 = (floatx4){b31, b31, b31, b31}; \
    AC00 = MFMA_(a, BX00, AC00); AC01 = MFMA_(a, BX01, AC01);           \
    AC10 = MFMA_(a, BX10, AC10); AC11 = MFMA_(a, BX11, AC11);           \
    AC20 = MFMA_(a, BX20, AC20); AC21 = MFMA_(a, BX21, AC21);           \
    AC30 = MFMA_(a, BX30, AC30); AC31 = MFMA_(a, BX31, AC31);           \
  }

  // ---- Prologue: stage x(0); x-phase for t=0 ----
  {
    int r = tid >> 5, c = tid & 31;
    bf16x8 x0 = ((const bf16x8*)(xb + (m_blk * 16 + r) * ND))[c];
    *(bf16x8*)(As + r * 264 + c * 8) = x0;
  }
  __syncthreads();
  XPHASE()

  for (int t = 0; t < NT; ++t) {
    // ---- Wait for my 4 source slots; then LLC->VGPR A-frags + 32 MFMAs ----
    {
      const unsigned tgt = (unsigned)t;  // h(t) published with value t
      while (true) {
        unsigned v = AL(&slots[sidx]);
        if (__all((int)(v >= tgt))) break;
        __builtin_amdgcn_s_sleep(1);
      }
      __asm__ __volatile__("" ::: "memory");  // no hoisting of h loads
      const __bf16* hrow = hbuf + (t & 1) * (NB * NH)
                         + (m_blk * 16 + n16) * NH + (wave << 7) + (q << 3);
      union { unsigned long long u[2]; bf16x8 v; } u0, u1, u2, u3;
      const unsigned long long* hp0 = (const unsigned long long*)(hrow);
      const unsigned long long* hp1 = (const unsigned long long*)(hrow + 32);
      const unsigned long long* hp2 = (const unsigned long long*)(hrow + 64);
      const unsigned long long* hp3 = (const unsigned long long*)(hrow + 96);
      u0.u[0] = AL(hp0); u0.u[1] = AL(hp0 + 1);
      u1.u[0] = AL(hp1); u1.u[1] = AL(hp1 + 1);
      u2.u[0] = AL(hp2); u2.u[1] = AL(hp2 + 1);
      u3.u[0] = AL(hp3); u3.u[1] = AL(hp3 + 1);
      bf16x8 a0 = u0.v, a1 = u1.v, a2 = u2.v, a3 = u3.v;
      AC00 = MFMA_(a0, BH000, AC00); AC01 = MFMA_(a0, BH010, AC01);
      AC10 = MFMA_(a0, BH100, AC10); AC11 = MFMA_(a0, BH110, AC11);
      AC20 = MFMA_(a0, BH200, AC20); AC21 = MFMA_(a0, BH210, AC21);
      AC30 = MFMA_(a0, BH300, AC30); AC31 = MFMA_(a0, BH310, AC31);
      AC00 = MFMA_(a1, BH001, AC00); AC01 = MFMA_(a1, BH011, AC01);
      AC10 = MFMA_(a1, BH101, AC10); AC11 = MFMA_(a1, BH111, AC11);
      AC20 = MFMA_(a1, BH201, AC20); AC21 = MFMA_(a1, BH211, AC21);
      AC30 = MFMA_(a1, BH301, AC30); AC31 = MFMA_(a1, BH311, AC31);
      AC00 = MFMA_(a2, BH002, AC00); AC01 = MFMA_(a2, BH012, AC01);
      AC10 = MFMA_(a2, BH102, AC10); AC11 = MFMA_(a2, BH112, AC11);
      AC20 = MFMA_(a2, BH202, AC20); AC21 = MFMA_(a2, BH212, AC21);
      AC30 = MFMA_(a2, BH302, AC30); AC31 = MFMA_(a2, BH312, AC31);
      AC00 = MFMA_(a3, BH003, AC00); AC01 = MFMA_(a3, BH013, AC01);
      AC10 = MFMA_(a3, BH103, AC10); AC11 = MFMA_(a3, BH113, AC11);
      AC20 = MFMA_(a3, BH203, AC20); AC21 = MFMA_(a3, BH213, AC21);
      AC30 = MFMA_(a3, BH303, AC30); AC31 = MFMA_(a3, BH313, AC31);
    }

    // ---- Issue x(t+1) load (flies during reduction + S2 + cell) ----
    bf16x8 xv;
    if (t < NT - 1)
      xv = ((const bf16x8*)(xb + ((t + 1) * NB + m_blk * 16 + (tid >> 5)) * ND))[tid & 31];

    // ---- Reduction: wave partials -> Gs[wave] ----
#pragma unroll
    for (int rr = 0; rr < 4; ++rr) {
      int row = q * 4 + rr;
      Gs[wave][row][n16]       = AC00[rr];
      Gs[wave][row][16 + n16]  = AC01[rr];
      Gs[wave][row][32 + n16]  = AC10[rr];
      Gs[wave][row][48 + n16]  = AC11[rr];
      Gs[wave][row][64 + n16]  = AC20[rr];
      Gs[wave][row][80 + n16]  = AC21[rr];
      Gs[wave][row][96 + n16]  = AC30[rr];
      Gs[wave][row][112 + n16] = AC31[rr];
    }
    __syncthreads();  // S2: gates ready, As x-region consumed (by XPHASE)

    // ---- Write x(t+1) into As (consumed by XPHASE after S3) ----
    if (t < NT - 1)
      *(bf16x8*)(As + (tid >> 5) * 264 + (tid & 31) * 8) = xv;

    // ---- LSTM cell: sum 8 wave-partials per gate; fast nonlinearities ----
    {
      float xi = 0.f, xf = 0.f, xg = 0.f, xo = 0.f;
#pragma unroll
      for (int w2 = 0; w2 < 8; ++w2) {
        xi += Gs[w2][r_e][c_e];
        xf += Gs[w2][r_e][32 + c_e];
        xg += Gs[w2][r_e][64 + c_e];
        xo += Gs[w2][r_e][96 + c_e];
      }
      float iv = fsigmoid_(xi);
      float fv = fsigmoid_(xf);
      float gv = fsoftplus_(xg);
      float ov = fsigmoid_(xo);
      c_state = fv * c_state + iv * gv;
      float hv = ov * fsoftplus_(c_state);
      if (t == NT - 1) {
        hlast[grow * NH + hcol] = hv;
      } else {
        // 8B packed publish: 2x shfl_xor, lanes c_e%4==0 store
        float hn1 = __shfl_xor(hv, 1);
        __hip_bfloat162 pk;
        pk.x = (__hip_bfloat16)hv; pk.y = (__hip_bfloat16)hn1;
        unsigned int p = *(unsigned int*)&pk;
        unsigned int po = (unsigned int)__shfl_xor((int)p, 2);
        if ((c_e & 3) == 0) {
          unsigned long long v = ((unsigned long long)po << 32) | p;
          __hip_atomic_store(
              (unsigned long long*)(hbuf + ((t + 1) & 1) * (NB * NH)
                                    + grow * NH + hcol),
              v, __ATOMIC_RELAXED, __HIP_MEMORY_SCOPE_AGENT);
        }
      }
    }

    if (t < NT - 1) {
      __syncthreads();  // S3: publish stores drained (vmcnt), x-region visible
      if (tid == 0) {
        __hip_atomic_store(&slots[slot_base + n_blk], (unsigned)(t + 1),
                           __ATOMIC_RELEASE, __HIP_MEMORY_SCOPE_AGENT);
      }
      // Hidden work while peers converge: x-GEMM + acc init for t+1
      XPHASE()
    }
  }
#undef XPHASE
#undef AL
#undef MFMA_
}

// ---------------------------------------------------------------------------
// Kernel 3: projection head. 32 blocks x 128 thr; 4 batch rows per block.
// ---------------------------------------------------------------------------
__global__ __launch_bounds__(128) void proj_kernel(
    const float* __restrict__ hlast,
    const float* __restrict__ Wm, const float* __restrict__ bm,
    const float* __restrict__ Wv, const float* __restrict__ bv,
    const float* __restrict__ eps, float* __restrict__ out) {
  __shared__ float hs[4][NH];
  const int bb = blockIdx.x * 4;
  for (int idx = threadIdx.x; idx < 4 * NH; idx += 128)
    hs[idx >> 10][idx & (NH - 1)] = hlast[(bb + (idx >> 10)) * NH + (idx & (NH - 1))];
  __syncthreads();
  const int z = threadIdx.x;
  float am[4] = {0.f, 0.f, 0.f, 0.f};
  float av[4] = {0.f, 0.f, 0.f, 0.f};
#pragma unroll 8
  for (int k = 0; k < NH; ++k) {
    float wm = Wm[k * NZ + z];
    float wv = Wv[k * NZ + z];
#pragma unroll
    for (int r = 0; r < 4; ++r) {
      am[r] += hs[r][k] * wm;
      av[r] += hs[r][k] * wv;
    }
  }
#pragma unroll
  for (int r = 0; r < 4; ++r) {
    int b = bb + r;
    float mu = am[r] + bm[z];
    float lv = av[r] + bv[z];
    float zz = mu + eps[b * NZ + z] * expf(0.5f * lv);
    out[b * NZ + z] = mu;
    out[NB * NZ + b * NZ + z] = lv;
    out[2 * NB * NZ + b * NZ + z] = zz;
  }
}

// ---------------------------------------------------------------------------
extern "C" void kernel_launch(void* const* d_in, const int* in_sizes, int n_in,
                              void* d_out, int out_size, void* d_ws, size_t ws_size,
                              hipStream_t stream) {
  const float* x   = (const float*)d_in[0];
  const float* W   = (const float*)d_in[1];
  const float* U   = (const float*)d_in[2];
  const float* b   = (const float*)d_in[3];
  const float* Wm  = (const float*)d_in[4];
  const float* bm  = (const float*)d_in[5];
  const float* Wv  = (const float*)d_in[6];
  const float* bv  = (const float*)d_in[7];
  const float* eps = (const float*)d_in[8];

  // Workspace layout:
  //   [0,       524288)   hbuf: 2 x B x H bf16
  //   [524288,  1048576)  hlast: B x H fp32
  //   [1048576, 1049600)  slots: 256 x u32 (padded to 4096)
  //   [1052672, +33.5MB)  xb: T x B x D bf16
  char* ws = (char*)d_ws;
  __bf16* hbuf = (__bf16*)ws;
  float* hlast = (float*)(ws + 524288);
  unsigned int* slots = (unsigned int*)(ws + 1048576);
  __bf16* xb = (__bf16*)(ws + 1048576 + 4096);

  hipMemsetAsync(hbuf, 0, NB * NH * sizeof(__bf16), stream);  // h_0 = 0
  hipMemsetAsync(slots, 0, 256 * sizeof(unsigned int), stream);

  convert_x_kernel<<<dim3((NB * NT * ND) / 4 / 256), dim3(256), 0, stream>>>(
      (const float4*)x, xb);

  void* args[] = {(void*)&xb, (void*)&W, (void*)&U, (void*)&b,
                  (void*)&hbuf, (void*)&hlast, (void*)&slots};
  hipLaunchCooperativeKernel(reinterpret_cast<void*>(lstm_persistent),
                             dim3(256), dim3(512), args, 0, stream);

  proj_kernel<<<dim3(32), dim3(128), 0, stream>>>(hlast, Wm, bm, Wv, bv, eps,
                                                  (float*)d_out);
}